// Round 1
// baseline (153.448 us; speedup 1.0000x reference)
//
#include <hip/hip_runtime.h>
#include <math.h>

#define HF 96
#define WF 160
#define CH 100
#define HH 48      // HF/2
#define HW 80      // WF/2
#define MD 9       // MAX_DISTANCE
#define KD 19      // 2*MD+1
#define K2 361     // KD*KD
#define NMAX 8

// workspace float offsets
#define OFF_X   0
#define OFF_Y   (HH*HW*CH)                 // 384000
#define OFF_XS  (2*HH*HW*CH)               // 768000
#define OFF_YS  (2*HH*HW*CH + HH*HW)       // 771840
#define OFF_DH  (2*HH*HW*CH + 2*HH*HW)     // 775680
// total floats: 775680 + 3840*361 = 2161920 (~8.65 MB)

// Kernel A: 2x2 avg-pool both embeddings + per-pixel squared norms.
// grid = HH*HW blocks, 128 threads (c dimension).
__global__ __launch_bounds__(128) void pool_kernel(
    const float* __restrict__ q,   // query  (-> x)
    const float* __restrict__ p,   // prev   (-> y)
    float* __restrict__ x, float* __restrict__ y,
    float* __restrict__ xs, float* __restrict__ ys) {
  int pix = blockIdx.x;
  int i = pix / HW, j = pix % HW;
  int c = threadIdx.x;
  __shared__ float red[2][128];
  float xv = 0.f, yv = 0.f;
  if (c < CH) {
    int base = (2 * i) * WF * CH + (2 * j) * CH + c;
    xv = 0.25f * (q[base] + q[base + CH] + q[base + WF * CH] + q[base + WF * CH + CH]);
    yv = 0.25f * (p[base] + p[base + CH] + p[base + WF * CH] + p[base + WF * CH + CH]);
    x[pix * CH + c] = xv;
    y[pix * CH + c] = yv;
  }
  red[0][c] = xv * xv;
  red[1][c] = yv * yv;
  __syncthreads();
  for (int s = 64; s > 0; s >>= 1) {
    if (c < s) { red[0][c] += red[0][c + s]; red[1][c] += red[1][c + s]; }
    __syncthreads();
  }
  if (c == 0) { xs[pix] = red[0][0]; ys[pix] = red[1][0]; }
}

// Kernel B: local distances at half res, sigmoid-mapped.
// grid = HH*HW blocks (one per half-res pixel), 384 threads (361 offsets).
__global__ __launch_bounds__(384) void dist_kernel(
    const float* __restrict__ x, const float* __restrict__ y,
    const float* __restrict__ xs, const float* __restrict__ ys,
    float* __restrict__ dh) {
  int pix = blockIdx.x;
  int i = pix / HW, j = pix % HW;
  __shared__ __align__(16) float xl[CH];
  int t = threadIdx.x;
  if (t < CH) xl[t] = x[pix * CH + t];
  __syncthreads();
  if (t >= K2) return;
  int dy = t / KD, dx = t - dy * KD;
  int ii = i + dy - MD, jj = j + dx - MD;
  float r;
  if (ii < 0 || ii >= HH || jj < 0 || jj >= HW) {
    r = 1.0f;  // PAD_VAL saturates sigmoid exactly to 1 in fp32
  } else {
    int np = ii * HW + jj;
    const float4* yp = (const float4*)(y + np * CH);
    const float4* xp = (const float4*)xl;
    float dot = 0.f;
#pragma unroll
    for (int c4 = 0; c4 < CH / 4; ++c4) {
      float4 a = xp[c4], b = yp[c4];
      dot += a.x * b.x + a.y * b.y + a.z * b.z + a.w * b.w;
    }
    float s = xs[pix] + ys[np] - 2.f * dot;
    float e = __expf(-s);
    r = (1.f - e) / (1.f + e);   // == (sigmoid(s)-0.5)*2
  }
  dh[pix * K2 + t] = r;
}

// Kernel C: bilinear upsample (align_corners=True) + per-object masked min.
// One wave (64 lanes) per full-res pixel; block = 256 threads = 4 pixels.
// grid = HF*WF/4 = 3840 blocks.
__global__ __launch_bounds__(256) void upmin_kernel(
    const float* __restrict__ dh, const int* __restrict__ labels,
    const int* __restrict__ gt, int n, float* __restrict__ out) {
  int wid = threadIdx.x >> 6;
  int lane = threadIdx.x & 63;
  int pixel = blockIdx.x * 4 + wid;
  int I = pixel / WF, J = pixel - I * WF;

  const float sy = (float)((HH - 1.0) / (HF - 1.0));
  const float sx = (float)((HW - 1.0) / (WF - 1.0));
  float py = (float)I * sy;
  int y0 = (int)floorf(py); if (y0 > HH - 2) y0 = HH - 2; if (y0 < 0) y0 = 0;
  float fy = py - (float)y0;
  float px = (float)J * sx;
  int x0 = (int)floorf(px); if (x0 > HW - 2) x0 = HW - 2; if (x0 < 0) x0 = 0;
  float fx = px - (float)x0;

  const float* r00 = dh + (y0 * HW + x0) * K2;
  const float* r01 = r00 + K2;
  const float* r10 = r00 + HW * K2;
  const float* r11 = r10 + K2;
  float w00 = (1.f - fy) * (1.f - fx), w01 = (1.f - fy) * fx;
  float w10 = fy * (1.f - fx),         w11 = fy * fx;

  int gtl[NMAX];
  for (int o = 0; o < n; ++o) gtl[o] = gt[o];
  float mins[NMAX];
  for (int o = 0; o < NMAX; ++o) mins[o] = 1.0f;

  for (int k = lane; k < K2; k += 64) {
    int dy = k / KD, dx = k - dy * KD;
    int P = I + dy - MD, Q = J + dx - MD;
    if (P < 0 || P >= HF || Q < 0 || Q >= WF) continue;
    int lab = labels[P * WF + Q];
    float v = w00 * r00[k] + w01 * r01[k] + w10 * r10[k] + w11 * r11[k];
    for (int o = 0; o < n; ++o)
      if (lab == gtl[o]) mins[o] = fminf(mins[o], v);
  }
  for (int s = 32; s > 0; s >>= 1)
    for (int o = 0; o < n; ++o)
      mins[o] = fminf(mins[o], __shfl_down(mins[o], s));
  if (lane == 0)
    for (int o = 0; o < n; ++o) out[pixel * n + o] = mins[o];
}

extern "C" void kernel_launch(void* const* d_in, const int* in_sizes, int n_in,
                              void* d_out, int out_size, void* d_ws, size_t ws_size,
                              hipStream_t stream) {
  const float* prev  = (const float*)d_in[0];   // prev_frame_embedding -> y
  const float* query = (const float*)d_in[1];   // query_embedding      -> x
  const int* labels  = (const int*)d_in[2];
  const int* gt      = (const int*)d_in[3];
  int n = in_sizes[3];
  if (n > NMAX) n = NMAX;
  float* ws = (float*)d_ws;
  float* x  = ws + OFF_X;
  float* y  = ws + OFF_Y;
  float* xs = ws + OFF_XS;
  float* ys = ws + OFF_YS;
  float* dh = ws + OFF_DH;
  float* out = (float*)d_out;

  hipLaunchKernelGGL(pool_kernel, dim3(HH * HW), dim3(128), 0, stream,
                     query, prev, x, y, xs, ys);
  hipLaunchKernelGGL(dist_kernel, dim3(HH * HW), dim3(384), 0, stream,
                     x, y, xs, ys, dh);
  hipLaunchKernelGGL(upmin_kernel, dim3(HF * WF / 4), dim3(256), 0, stream,
                     dh, labels, gt, n, out);
}